// Round 4
// baseline (131.763 us; speedup 1.0000x reference)
//
#include <hip/hip_runtime.h>
#include <math.h>

typedef _Float16 half8 __attribute__((ext_vector_type(8)));
typedef float floatx4 __attribute__((ext_vector_type(4)));

union U16 { uint4 u; half8 h; };

// ---------------------------------------------------------------------------
// prep: ONE kernel, 133 blocks x 512 threads, no atomics, no second pass.
//  [0,64):    R rows d0=4*bid..+4, K=1024 split across s=tid>>8 halves,
//             LDS partial reduce.  (Wh L2 traffic: 64 x 1MB = 64 MB)
//  [64,128):  a/bv rows r0=8*(bid-64)..+8, K=256 split in halves; a += Whb.
//  [128,132): WmT2 f16 granule pack: WmT2[(kb*256+h)] = Wm[kb*8..+8][h]
//  [132]:     WoPk f16 granule pack (c<5 real, else 0)
// ---------------------------------------------------------------------------
__global__ __launch_bounds__(512) void k_prep(
    const float* __restrict__ hs, const float* __restrict__ Wh,
    const float* __restrict__ Whb, const float* __restrict__ Wo,
    float* __restrict__ R, float* __restrict__ a, float* __restrict__ bv,
    uint4* __restrict__ WmT2, uint4* __restrict__ WoPk)
{
  __shared__ __align__(16) char pool[32768];
  int bid = blockIdx.x, tid = threadIdx.x;

  if (bid < 64) {                        // ---- R ----
    float (*tbl)[4] = (float(*)[4])pool;            // [1024 k][4 d] = 16 KB
    float* part = (float*)(pool + 16384);           // [4 d][256 h] = 4 KB
    int d0 = bid * 4;
    for (int idx = tid; idx < 4096; idx += 512) {
      int k = idx >> 2, dl = idx & 3;
      float e = (float)(k & ~1) * (1.0f / 1024.f);
      float div = powf(10000.f, e);
      float ang = (float)(d0 + dl) / div;
      tbl[k][dl] = (k & 1) ? cosf(ang) : sinf(ang);
    }
    __syncthreads();
    int h = tid & 255, s = tid >> 8;
    float acc[4] = {0.f, 0.f, 0.f, 0.f};
    for (int kk = 0; kk < 512; ++kk) {
      int k = s * 512 + kk;
      float wv = Wh[k * 256 + h];
      float4 tr = *(const float4*)&tbl[k][0];
      acc[0] = fmaf(tr.x, wv, acc[0]);
      acc[1] = fmaf(tr.y, wv, acc[1]);
      acc[2] = fmaf(tr.z, wv, acc[2]);
      acc[3] = fmaf(tr.w, wv, acc[3]);
    }
    if (s) {
#pragma unroll
      for (int dl = 0; dl < 4; ++dl) part[dl * 256 + h] = acc[dl];
    }
    __syncthreads();
    if (!s) {
#pragma unroll
      for (int dl = 0; dl < 4; ++dl)
        if (d0 + dl < 255)
          R[(d0 + dl) * 256 + h] = acc[dl] + part[dl * 256 + h];
    }

  } else if (bid < 128) {                // ---- a / bv (a includes Whb) ----
    float (*xs)[8] = (float(*)[8])pool;             // [256 k][8 r] = 8 KB
    float* pa = (float*)(pool + 8192);              // [8][256] = 8 KB
    float* pb = (float*)(pool + 16384);             // [8][256] = 8 KB
    int r0 = (bid - 64) * 8;
    for (int idx = tid; idx < 2048; idx += 512) {
      int k = idx & 255, r = idx >> 8;
      xs[k][r] = hs[(r0 + r) * 256 + k];
    }
    __syncthreads();
    int h = tid & 255, s = tid >> 8;
    float aa[8] = {0, 0, 0, 0, 0, 0, 0, 0}, bb[8] = {0, 0, 0, 0, 0, 0, 0, 0};
    for (int kk = 0; kk < 128; ++kk) {
      int k = s * 128 + kk;
      float we = Wh[k * 256 + h];
      float wsv = Wh[(256 + k) * 256 + h];
      float wd = Wh[(512 + k) * 256 + h];
      float wA = we + wd, wB = wsv - wd;
      float xr[8];
      *(float4*)&xr[0] = *(const float4*)&xs[k][0];
      *(float4*)&xr[4] = *(const float4*)&xs[k][4];
#pragma unroll
      for (int r = 0; r < 8; ++r) {
        aa[r] = fmaf(xr[r], wA, aa[r]);
        bb[r] = fmaf(xr[r], wB, bb[r]);
      }
    }
    if (s) {
#pragma unroll
      for (int r = 0; r < 8; ++r) { pa[r * 256 + h] = aa[r]; pb[r * 256 + h] = bb[r]; }
    }
    __syncthreads();
    if (!s) {
      float bias = Whb[h];
#pragma unroll
      for (int r = 0; r < 8; ++r) {
        a[(r0 + r) * 256 + h] = aa[r] + pa[r * 256 + h] + bias;
        bv[(r0 + r) * 256 + h] = bb[r] + pb[r * 256 + h];
      }
    }

  } else if (bid < 132) {                // ---- WmT2 pack ----
    _Float16 (*T)[256] = (_Float16(*)[256])pool;    // [64 k][256 h] = 32 KB
    int q = bid - 128;
    for (int idx = tid; idx < 16384; idx += 512) {
      int k = idx >> 8, h = idx & 255;
      T[k][h] = (_Float16)Wh[(768 + q * 64 + k) * 256 + h];
    }
    __syncthreads();
    for (int gi = tid; gi < 2048; gi += 512) {
      int kbl = gi >> 8, h = gi & 255;
      U16 v;
#pragma unroll
      for (int e = 0; e < 8; ++e) v.h[e] = T[kbl * 8 + e][h];
      WmT2[(q * 8 + kbl) * 256 + h] = v.u;
    }

  } else {                               // ---- WoPk pack ----
    for (int gi = tid; gi < 512; gi += 512) {
      int kb = gi >> 4, c = gi & 15;
      U16 v;
#pragma unroll
      for (int e = 0; e < 8; ++e)
        v.h[e] = (c < 5) ? (_Float16)Wo[(kb * 8 + e) * 5 + c] : (_Float16)0.f;
      WoPk[gi] = v.u;
    }
  }
}

// ---------------------------------------------------------------------------
// main: 2048 blocks = (b, i-pair, j-tile 32); 4 waves split h' (64 each).
// P = 64 pairs (2i x 32j) per block -> Wm L2 traffic halved vs R3; per kstep
// 16 MFMA : 4 ds_read : 4 global. acc init = a_i(+bias) + bv_j + R_d.
// Epilogue: tanh -> f16 P (64 rows) in As -> all 4 waves do 16-row Wo GEMM.
// ---------------------------------------------------------------------------
__global__ __launch_bounds__(256, 3) void k_main(
    const float* __restrict__ hs, const int* __restrict__ mask,
    const float* __restrict__ R, const float* __restrict__ a,
    const float* __restrict__ bvec, const uint4* __restrict__ WmT2,
    const uint4* __restrict__ WoPk, const float* __restrict__ Wob,
    float* __restrict__ out)
{
  __shared__ __align__(16) _Float16 As[2][32][264];  // 33.8 KB

  int bid = blockIdx.x, tid = threadIdx.x;
  int jt = bid & 7, ig = (bid >> 3) & 127, b = bid >> 10;
  int i0 = ig * 2, j0 = jt * 32;
  int lane = tid & 63, w = tid >> 6;
  int c16 = lane & 15, quad = lane >> 4;
  const float* hsb = hs + (size_t)b * 65536;

  // ---- acc init: a_i(+bias) + bv_j + R_{j-i} ----
  float av[2][4];
#pragma unroll
  for (int i2 = 0; i2 < 2; ++i2)
#pragma unroll
    for (int ht2 = 0; ht2 < 4; ++ht2)
      av[i2][ht2] = a[((size_t)(b * 256 + i0 + i2)) * 256 + 64 * w + 16 * ht2 + c16];

  floatx4 acc[2][2][4];  // [i2][jt2][ht2]
#pragma unroll
  for (int jt2 = 0; jt2 < 2; ++jt2) {
#pragma unroll
    for (int r = 0; r < 4; ++r) {
      int jg = j0 + jt2 * 16 + quad * 4 + r;
      float bvv[4];
#pragma unroll
      for (int ht2 = 0; ht2 < 4; ++ht2)
        bvv[ht2] = bvec[((size_t)(b * 256 + jg)) * 256 + 64 * w + 16 * ht2 + c16];
#pragma unroll
      for (int i2 = 0; i2 < 2; ++i2) {
        int dd = jg - (i0 + i2);
        dd = dd < -127 ? -127 : (dd > 127 ? 127 : dd);
        dd += 127;
        const float* rp = R + (size_t)dd * 256 + 64 * w;
#pragma unroll
        for (int ht2 = 0; ht2 < 4; ++ht2)
          acc[i2][jt2][ht2][r] = av[i2][ht2] + bvv[ht2] + rp[16 * ht2 + c16];
      }
    }
  }

  // ---- A tiles: As[i2][j][k] = f16(x_{i0+i2}[k] * x_{j0+j}[k]) ----
  for (int idx = tid; idx < 2048; idx += 256) {
    int i2 = idx >> 10, j = (idx >> 5) & 31, k8 = (idx & 31) * 8;
    float4 xi0 = *(const float4*)(hsb + (i0 + i2) * 256 + k8);
    float4 xi1 = *(const float4*)(hsb + (i0 + i2) * 256 + k8 + 4);
    float4 xj0 = *(const float4*)(hsb + (j0 + j) * 256 + k8);
    float4 xj1 = *(const float4*)(hsb + (j0 + j) * 256 + k8 + 4);
    half8 p = {(_Float16)(xi0.x * xj0.x), (_Float16)(xi0.y * xj0.y),
               (_Float16)(xi0.z * xj0.z), (_Float16)(xi0.w * xj0.w),
               (_Float16)(xi1.x * xj1.x), (_Float16)(xi1.y * xj1.y),
               (_Float16)(xi1.z * xj1.z), (_Float16)(xi1.w * xj1.w)};
    *(half8*)(&As[i2][j][k8]) = p;
  }
  __syncthreads();

  // ---- K loop (barrier-free): B-frags from L2, A-frags from LDS ----
#pragma unroll 1
  for (int kc = 0; kc < 4; ++kc) {
#pragma unroll
    for (int ks = 0; ks < 2; ++ks) {
      int kb = kc * 8 + ks * 4 + quad;
      U16 bg[4];
#pragma unroll
      for (int ht2 = 0; ht2 < 4; ++ht2)
        bg[ht2].u = WmT2[kb * 256 + 64 * w + 16 * ht2 + c16];
      half8 af[2][2];
#pragma unroll
      for (int i2 = 0; i2 < 2; ++i2)
#pragma unroll
        for (int jt2 = 0; jt2 < 2; ++jt2)
          af[i2][jt2] =
              *(const half8*)(&As[i2][jt2 * 16 + c16][kc * 64 + ks * 32 + quad * 8]);
#pragma unroll
      for (int i2 = 0; i2 < 2; ++i2)
#pragma unroll
        for (int jt2 = 0; jt2 < 2; ++jt2)
#pragma unroll
          for (int ht2 = 0; ht2 < 4; ++ht2)
            acc[i2][jt2][ht2] = __builtin_amdgcn_mfma_f32_16x16x32_f16(
                af[i2][jt2], bg[ht2].h, acc[i2][jt2][ht2], 0, 0, 0);
    }
  }

  __syncthreads();  // all A-frag reads complete before P overwrites As

  // ---- P = tanh(acc) -> f16 into As (row g = i2*32 + jl) ----
#pragma unroll
  for (int i2 = 0; i2 < 2; ++i2)
#pragma unroll
    for (int jt2 = 0; jt2 < 2; ++jt2)
#pragma unroll
      for (int ht2 = 0; ht2 < 4; ++ht2) {
        int hp = 64 * w + 16 * ht2 + c16;
#pragma unroll
        for (int r = 0; r < 4; ++r) {
          int jl = jt2 * 16 + quad * 4 + r;
          float x = acc[i2][jt2][ht2][r];
          float t = 1.f - 2.f / (__expf(2.f * x) + 1.f);  // tanh, inf-safe
          As[i2][jl][hp] = (_Float16)t;
        }
      }
  __syncthreads();

  // ---- epilogue GEMM: wave w -> P rows [16w,16w+16) x 16c, K=256 ----
  U16 wog[8];
#pragma unroll
  for (int s = 0; s < 8; ++s) wog[s].u = WoPk[(s * 4 + quad) * 16 + c16];
  floatx4 accE = {0.f, 0.f, 0.f, 0.f};
  int arow = 16 * w + c16;
  int i2a = arow >> 5, jla = arow & 31;
#pragma unroll
  for (int s = 0; s < 8; ++s) {
    half8 ae = *(const half8*)(&As[i2a][jla][s * 32 + quad * 8]);
    accE = __builtin_amdgcn_mfma_f32_16x16x32_f16(ae, wog[s].h, accE, 0, 0, 0);
  }

  const int* mb = mask + b * 256;
  float wob = (c16 < 5) ? Wob[c16] : 0.f;
#pragma unroll
  for (int r = 0; r < 4; ++r) {
    int grow = 16 * w + quad * 4 + r;
    int ii = i0 + (grow >> 5), jg = j0 + (grow & 31);
    float v = accE[r] + wob;
    if (!(mb[ii] && mb[jg])) v = -INFINITY;
    if (jg < ii) v -= 1e12f;
    if (c16 < 5) out[(((size_t)b * 5 + c16) * 256 + ii) * 256 + jg] = v;
  }
}

extern "C" void kernel_launch(void* const* d_in, const int* in_sizes, int n_in,
                              void* d_out, int out_size, void* d_ws, size_t ws_size,
                              hipStream_t stream) {
  const float* hs   = (const float*)d_in[0];
  const int*   mask = (const int*)d_in[1];
  const float* Wh_w = (const float*)d_in[2];
  const float* Wh_b = (const float*)d_in[3];
  const float* Wo_w = (const float*)d_in[4];
  const float* Wo_b = (const float*)d_in[5];

  char* ws = (char*)d_ws;
  float* R    = (float*)(ws + 0);        // 255*256*4 (pad 256K)
  float* a    = (float*)(ws + 262144);   // 512*256*4
  float* bv   = (float*)(ws + 786432);   // 512*256*4
  uint4* WmT2 = (uint4*)(ws + 1310720);  // 256*256*2
  uint4* WoPk = (uint4*)(ws + 1441792);  // 512*16

  k_prep<<<133, 512, 0, stream>>>(hs, Wh_w, Wh_b, Wo_w, R, a, bv, WmT2, WoPk);
  k_main<<<2048, 256, 0, stream>>>(hs, mask, R, a, bv, WmT2, WoPk, Wo_b,
                                   (float*)d_out);
}